// Round 9
// baseline (106667.090 us; speedup 1.0000x reference)
//
#include <hip/hip_runtime.h>

// GRU, round 9: hoisted igates GEMM + slim persistent kernel, fixed partition.
//
// r8 regression diagnosed from counters: pollers shared WAVES with the
// store/IG-load thread -> wave-shared vmcnt destroyed the counted poll ring
// (round-5 store-ack bug at wave granularity); 8B split stores doubled
// per-line straggler events (WRITE_SIZE exactly 4x); __syncthreads' vmcnt(0)
// drain killed ring persistence. Fixes:
//  - poller waves are DEDICATED (tid 512..767; vmcnt queue = poll loads only)
//  - one 16B store per comm line (2 rows per wave, packed via 1 shuffle)
//  - raw s_barrier + lgkmcnt(0)-only flush (no vmcnt drain at barriers)
//  - single barrier per step; gates fully in-wave (no gsum/isum/xstage LDS)
// Comm protocol unchanged (r1-proven): tagged 8B words {val|step}, 2 per 16B
// line, parity double-buffered, sc0+sc1.

#define T_STEPS    32768
#define INSZ       256
#define HSZ        512
#define NWG        32
#define TPB        768        // 8 matvec waves + 4 poller waves
#define POLL_GUARD 16384

typedef unsigned long long u64;
typedef unsigned int u32;
typedef u32 u32x4 __attribute__((ext_vector_type(4)));
typedef float f32x4 __attribute__((ext_vector_type(4)));
typedef float f32x2 __attribute__((ext_vector_type(2)));

__device__ __forceinline__ int hpad(int k) { return k + 4 * (k >> 5); }

__device__ __forceinline__ void st16_sys(u64* p, u32x4 v) {
  asm volatile("global_store_dwordx4 %0, %1, off sc0 sc1" :: "v"(p), "v"(v) : "memory");
}

// raw workgroup barrier: flush LDS writes (lgkm) but do NOT drain vmcnt --
// poller ring loads and producer store-acks stay in flight across steps.
__device__ __forceinline__ void barrier_lds_only() {
  asm volatile("s_waitcnt lgkmcnt(0)\n\ts_barrier" ::: "memory");
}

// Re-init every call (harness does not re-poison d_ws between graph replays).
__global__ void init_comm(u64* __restrict__ comm, const float* __restrict__ h0) {
  int jj = threadIdx.x;                      // 0..511
  u32 bits = __float_as_uint(h0[jj]);
  comm[jj]       = (u64)bits;                // buf0: tag 0 | h0 value
  comm[HSZ + jj] = 0xFFFFFFFF00000000ull;    // buf1: invalid tag
}

// ---------------- Phase 1: igates GEMM (64x64 tiles, K=256; proven r8) -----
__launch_bounds__(256)
__global__ void igates_gemm(const float* __restrict__ input,
                            const float* __restrict__ w_ih,
                            const float* __restrict__ bias,
                            float* __restrict__ ig)
{
  const int t0 = blockIdx.x * 64;
  const int r0 = blockIdx.y * 64;
  const int tid = threadIdx.x;
  const int tx = tid & 15, ty = tid >> 4;
  __shared__ float As[64][68];
  __shared__ float Bs[64][68];
  float acc[4][4] = {};
  for (int kc = 0; kc < INSZ; kc += 64) {
    #pragma unroll
    for (int i = 0; i < 4; ++i) {
      const int rr = (tid >> 4) + 16 * i;
      f32x4 av = *(const f32x4*)&input[(size_t)(t0 + rr) * INSZ + kc + tx * 4];
      *(f32x4*)&As[rr][tx * 4] = av;
      f32x4 bv = *(const f32x4*)&w_ih[(size_t)(r0 + rr) * INSZ + kc + tx * 4];
      #pragma unroll
      for (int ci = 0; ci < 4; ++ci) Bs[tx * 4 + ci][rr] = bv[ci];
    }
    __syncthreads();
    #pragma unroll 16
    for (int kk = 0; kk < 64; ++kk) {
      float av[4], bv[4];
      #pragma unroll
      for (int a = 0; a < 4; ++a) av[a] = As[ty * 4 + a][kk];
      #pragma unroll
      for (int b = 0; b < 4; ++b) bv[b] = Bs[kk][tx * 4 + b];
      #pragma unroll
      for (int a = 0; a < 4; ++a)
        #pragma unroll
        for (int b = 0; b < 4; ++b) acc[a][b] += av[a] * bv[b];
    }
    __syncthreads();
  }
  #pragma unroll
  for (int a = 0; a < 4; ++a)
    #pragma unroll
    for (int b = 0; b < 4; ++b) {
      const int r = r0 + tx * 4 + b;
      ig[(size_t)(t0 + ty * 4 + a) * 1536 + r] = acc[a][b] + bias[r];
    }
}

// ---------------- Phase 2: persistent recurrence kernel ----------------
// Wave layout (per WG, 12 waves):
//   waves 0..7  : rows jA=wg*16+2w (lanes 0..23) and jB=jA+1 (lanes 32..55).
//                 Within a row-block: gate q = (lane&31)>>3, k-lane kl=lane&7,
//                 64 MACs on k-chunk [64kl, 64kl+64). Lanes 24-31/56-63 idle.
//   waves 8..11 : pollers; each lane owns one 16B comm line (256 total).
__launch_bounds__(TPB, 1)
__global__ void gru_fast(const float* __restrict__ IG,     // [T][1536] (+bias)
                         const float* __restrict__ init_hidden,
                         const float* __restrict__ w_hh,
                         const float* __restrict__ bias_n,
                         u64* __restrict__ comm,
                         float* __restrict__ out)
{
  const int tid  = threadIdx.x;
  const int wg   = blockIdx.x;
  const int wv   = tid >> 6;                 // 0..11
  const int lane = tid & 63;
  const bool pol = (wv >= 8);
  const int  pt  = (wv - 8) * 64 + lane;     // poller line 0..255 (iff pol)

  const int sub = lane >> 5;                 // 0=row A, 1=row B
  const int ll  = lane & 31;
  const int q   = ll >> 3;                   // gate 0..2
  const int kl  = ll & 7;                    // k-lane 0..7
  const bool mv = (!pol) && (ll < 24);
  const int j   = wg * 16 + 2 * wv + sub;    // owned h row (iff !pol)

  // ---- whh: 64 f32 (16 quads) per mv lane; structurally register-resident ----
  f32x4 whh[16];
  if (mv) {
    const float* rp = w_hh + (size_t)(j + 512 * q) * HSZ + kl * 64;
    #pragma unroll
    for (int c = 0; c < 16; ++c) whh[c] = *(const f32x4*)(rp + c * 4);
  }
  // ---- gate-lane state (ll==0: lanes 0 and 32) ----
  float hold = 0.f, bn_ = 0.f, ig_r = 0.f, ig_z = 0.f, ig_n = 0.f;
  if (!pol && ll == 0) {
    hold = init_hidden[j];
    bn_  = bias_n[j];
    ig_r = IG[j]; ig_z = IG[512 + j]; ig_n = IG[1024 + j];
  }

  __shared__ float h_lds[2][HSZ + 4 * (HSZ >> 5)];

  u32x4 pa, pb, pc, pd, win;

#define ISSUE(Rr) \
  asm volatile("global_load_dwordx4 %0, %1, off sc0 sc1" : "=&v"(Rr) : "v"(lp) : "memory")
#define CHECK(Rr) \
  asm volatile("s_waitcnt vmcnt(3)" : "+v"(Rr)); \
  __builtin_amdgcn_sched_barrier(0); \
  if ((Rr[1] == tt && Rr[3] == tt) || --guard == 0) { win = Rr; break; } \
  ISSUE(Rr)

  // prologue: fill the perpetual ring (parity-0 buffer holds tag 0 already)
  if (pol) {
    const u64* lp = comm + 2 * pt;
    ISSUE(pa); ISSUE(pb); ISSUE(pc); ISSUE(pd);
  }

  for (int t = 0; t < T_STEPS; ++t) {
    const int p  = t & 1;
    const u32 tt = (u32)t;

    // ---- poll h_t (dedicated waves; vmcnt queue = poll loads only) ----
    if (pol) {
      const u64* lp = comm + (size_t)p * HSZ + 2 * pt;
      int guard = POLL_GUARD;
      win = pa;
      for (;;) {
        CHECK(pa);
        CHECK(pb);
        CHECK(pc);
        CHECK(pd);
      }
      f32x2 hv;
      hv[0] = __uint_as_float(win[0]);
      hv[1] = __uint_as_float(win[2]);
      *(f32x2*)&h_lds[p][hpad(2 * pt)] = hv;
    }
    barrier_lds_only();   // the ONLY barrier per step; no vmcnt drain

    if (!pol) {
      // ---- hh matvec: 64 MAC per active lane ----
      float a = 0.f;
      if (mv) {
        const float* hp = &h_lds[p][kl * 72];        // hpad(64*kl)
        #pragma unroll
        for (int c = 0; c < 8; ++c) {
          f32x4 hv4 = *(const f32x4*)(hp + c * 4);
          #pragma unroll
          for (int u = 0; u < 4; ++u) a += whh[c][u] * hv4[u];
        }
        const float* hp2 = hp + 36;                  // hpad(64*kl+32)
        #pragma unroll
        for (int c = 0; c < 8; ++c) {
          f32x4 hv4 = *(const f32x4*)(hp2 + c * 4);
          #pragma unroll
          for (int u = 0; u < 4; ++u) a += whh[8 + c][u] * hv4[u];
        }
      }
      // reduce over the 8 k-lanes (stays within each 8-aligned group)
      a += __shfl_xor(a, 1);
      a += __shfl_xor(a, 2);
      a += __shfl_xor(a, 4);
      // gate assembly: hr on own lane, hz/hn 1 group over (same wave)
      const int base = lane & 32;
      const float hz = __shfl(a, base + 8);
      const float hn = __shfl(a, base + 16);
      // gates on all lanes (only ll==0 lanes have valid inputs)
      const float reset = __builtin_amdgcn_rcpf(1.0f + __expf(-(ig_r + a)));
      const float upd   = __builtin_amdgcn_rcpf(1.0f + __expf(-(ig_z + hz)));
      const float e2    = __expf(2.0f * (ig_n + reset * (hn + bn_)));
      const float newv  = 1.0f - 2.0f * __builtin_amdgcn_rcpf(1.0f + e2);
      const float hnew  = newv + upd * (hold - newv);
      if (ll == 0) hold = hnew;
      // pack both rows of this wave into one 16B line store (lane 0)
      const float hB = __shfl(hnew, 32);
      if (lane == 0) {
        const int jA = wg * 16 + 2 * wv;
        u32x4 pk;
        pk[0] = __float_as_uint(hnew);  pk[1] = (u32)(t + 1);
        pk[2] = __float_as_uint(hB);    pk[3] = (u32)(t + 1);
        st16_sys(comm + (size_t)((t + 1) & 1) * HSZ + jA, pk);
        if (wg == 0 && wv == 0) out[t] = hnew;
      }
      // prefetch igates row t+1 (gate lanes; hidden under next full step)
      if (ll == 0) {
        const size_t bse = (size_t)((t + 1 < T_STEPS) ? (t + 1) : t) * 1536;
        ig_r = IG[bse + j]; ig_z = IG[bse + 512 + j]; ig_n = IG[bse + 1024 + j];
      }
    }
  }
#undef ISSUE
#undef CHECK
  asm volatile("s_waitcnt vmcnt(0)" ::: "memory");   // drain ring before endpgm
}

// ---------------- Fallback: proven round-7 kernel (ws too small) ------------
#define TPB_FB 1024
__device__ __forceinline__ int xpad(int k) { return k + ((k >> 4) << 2); }
__device__ __forceinline__ float grp_reduce16(float v) {
  v += __shfl_xor(v, 1);
  v += __shfl_xor(v, 2);
  v += __shfl_xor(v, 4);
  v += __shfl_xor(v, 8);
  return v;
}

__launch_bounds__(TPB_FB, 1)
__global__ void gru_persistent_fb(const float* __restrict__ input,
                                  const float* __restrict__ init_hidden,
                                  const float* __restrict__ w_ih,
                                  const float* __restrict__ w_hh,
                                  const float* __restrict__ bias,
                                  const float* __restrict__ bias_n,
                                  u64* __restrict__ comm,
                                  float* __restrict__ out)
{
  const int tid = threadIdx.x;
  const int wg  = blockIdx.x;
  const int g   = tid >> 4;
  const int l   = tid & 15;
  const bool mv = (g < 48);
  const int R   = wg * 16 + (g & 15) + 512 * (g >> 4);

  f32x4 whh[8];
  f32x4 wih[4];
  if (mv) {
    const float* rp = w_hh + (size_t)R * HSZ + l * 32;
    #pragma unroll
    for (int c = 0; c < 8; ++c) whh[c] = *(const f32x4*)(rp + c * 4);
    const float* rp2 = w_ih + (size_t)R * INSZ + l * 16;
    #pragma unroll
    for (int c = 0; c < 4; ++c) wih[c] = *(const f32x4*)(rp2 + c * 4);
  }
  float hold = 0.f, b_r = 0.f, b_z = 0.f, b_n = 0.f, bn = 0.f;
  if (tid < 16) {
    const int j = wg * 16 + tid;
    hold = init_hidden[j];
    b_r  = bias[j]; b_z = bias[j + 512]; b_n = bias[j + 1024];
    bn   = bias_n[j];
  }
  __shared__ float h_lds[2][HSZ + 4 * (HSZ >> 5)];
  __shared__ float gsum[48];
  __shared__ float isum[2][48];
  __shared__ float xstage[INSZ + (INSZ >> 4) * 4];

  if (tid >= 64 && tid < 128) {
    const int s = tid - 64;
    f32x4 v = *(const f32x4*)(input + s * 4);
    *(f32x4*)&xstage[xpad(s * 4)] = v;
  }
  __syncthreads();
  if (mv) {
    float a = 0.f;
    #pragma unroll
    for (int c = 0; c < 4; ++c) {
      f32x4 xv = *(const f32x4*)&xstage[20 * l + 4 * c];
      #pragma unroll
      for (int u = 0; u < 4; ++u) a += wih[c][u] * xv[u];
    }
    a = grp_reduce16(a);
    if (l == 0) isum[0][g] = a;
  }
  const bool poller = (tid >= 768);
  const int  pt     = tid - 768;
  u32x4 pa, pb, pc, pd, win;

#define ISSUE(Rr) \
  asm volatile("global_load_dwordx4 %0, %1, off sc0 sc1" : "=&v"(Rr) : "v"(lp) : "memory")
#define CHECK(Rr) \
  asm volatile("s_waitcnt vmcnt(3)" : "+v"(Rr)); \
  __builtin_amdgcn_sched_barrier(0); \
  if ((Rr[1] == tt && Rr[3] == tt) || --guard == 0) { win = Rr; break; } \
  ISSUE(Rr)

  for (int t = 0; t < T_STEPS; ++t) {
    const int p  = t & 1;
    const u32 tt = (u32)t;
    f32x4 xnew = {0.f, 0.f, 0.f, 0.f};
    if (tid >= 64 && tid < 128) {
      const int tn = (t + 1 < T_STEPS) ? (t + 1) : (T_STEPS - 1);
      xnew = *(const f32x4*)(input + (size_t)tn * INSZ + (tid - 64) * 4);
    }
    if (poller) {
      const u64* lp = comm + (size_t)p * HSZ + 2 * pt;
      ISSUE(pa); ISSUE(pb); ISSUE(pc); ISSUE(pd);
      int guard = POLL_GUARD;
      win = pa;
      for (;;) {
        CHECK(pa);
        CHECK(pb);
        CHECK(pc);
        CHECK(pd);
      }
      f32x2 hv;
      hv[0] = __uint_as_float(win[0]);
      hv[1] = __uint_as_float(win[2]);
      *(f32x2*)&h_lds[p][hpad(2 * pt)] = hv;
    }
    __syncthreads();
    if (mv) {
      float a = 0.f;
      const float* hp = &h_lds[p][l * 36];
      #pragma unroll
      for (int c = 0; c < 8; ++c) {
        f32x4 hv4 = *(const f32x4*)(hp + c * 4);
        #pragma unroll
        for (int u = 0; u < 4; ++u) a += whh[c][u] * hv4[u];
      }
      a = grp_reduce16(a);
      if (l == 0) gsum[g] = a;
    }
    if (tid >= 64 && tid < 128) *(f32x4*)&xstage[xpad((tid - 64) * 4)] = xnew;
    __syncthreads();
    if (tid < 16) {
      const int j = tid;
      const float hr = gsum[j], hz = gsum[16 + j], hn = gsum[32 + j];
      const float i_r = isum[p][j], i_z = isum[p][16 + j], i_n = isum[p][32 + j];
      const float reset = __builtin_amdgcn_rcpf(1.0f + __expf(-(i_r + b_r + hr)));
      const float upd   = __builtin_amdgcn_rcpf(1.0f + __expf(-(i_z + b_z + hz)));
      const float e2    = __expf(2.0f * (i_n + b_n + reset * (hn + bn)));
      const float newv  = 1.0f - 2.0f * __builtin_amdgcn_rcpf(1.0f + e2);
      const float hnew  = newv + upd * (hold - newv);
      hold = hnew;
      const float hpair = __shfl(hnew, tid + 1);
      if ((j & 1) == 0) {
        u64* nbuf = comm + (size_t)((t + 1) & 1) * HSZ;
        u32x4 pk;
        pk[0] = __float_as_uint(hnew);  pk[1] = (u32)(t + 1);
        pk[2] = __float_as_uint(hpair); pk[3] = (u32)(t + 1);
        st16_sys(&nbuf[wg * 16 + j], pk);
        if (wg == 0 && j == 0) out[t] = hnew;
      }
    }
    if (mv) {
      float a2 = 0.f;
      #pragma unroll
      for (int c = 0; c < 4; ++c) {
        f32x4 xv = *(const f32x4*)&xstage[20 * l + 4 * c];
        #pragma unroll
        for (int u = 0; u < 4; ++u) a2 += wih[c][u] * xv[u];
      }
      a2 = grp_reduce16(a2);
      if (l == 0) isum[(t + 1) & 1][g] = a2;
    }
  }
#undef ISSUE
#undef CHECK
}

extern "C" void kernel_launch(void* const* d_in, const int* in_sizes, int n_in,
                              void* d_out, int out_size, void* d_ws, size_t ws_size,
                              hipStream_t stream) {
  const float* input  = (const float*)d_in[0];
  const float* h0     = (const float*)d_in[1];
  const float* w_ih   = (const float*)d_in[2];
  const float* w_hh   = (const float*)d_in[3];
  const float* bias   = (const float*)d_in[4];
  const float* bias_n = (const float*)d_in[5];
  float* out = (float*)d_out;

  const size_t IG_BYTES = (size_t)T_STEPS * 1536 * sizeof(float);  // 201.3 MB

  if (ws_size >= IG_BYTES + 16384) {
    float* ig  = (float*)d_ws;
    u64*  comm = (u64*)((char*)d_ws + IG_BYTES);
    hipLaunchKernelGGL(init_comm, dim3(1), dim3(HSZ), 0, stream, comm, h0);
    hipLaunchKernelGGL(igates_gemm, dim3(T_STEPS / 64, 1536 / 64), dim3(256),
                       0, stream, input, w_ih, bias, ig);
    hipLaunchKernelGGL(gru_fast, dim3(NWG), dim3(TPB), 0, stream,
                       ig, h0, w_hh, bias_n, comm, out);
  } else {
    u64* comm = (u64*)d_ws;
    hipLaunchKernelGGL(init_comm, dim3(1), dim3(HSZ), 0, stream, comm, h0);
    hipLaunchKernelGGL(gru_persistent_fb, dim3(NWG), dim3(TPB_FB), 0, stream,
                       input, h0, w_ih, w_hh, bias, bias_n, comm, out);
  }
}

// Round 10
// 51804.639 us; speedup vs baseline: 2.0590x; 2.0590x over previous
//
#include <hip/hip_runtime.h>

// GRU, round 10: r7 structure verbatim + hoisted igates + no-vmcnt barriers.
//
// r9 post-mortem (counters): 64 weight f32/lane broke register residency
// (VGPR=64 cliff; r7's 32/lane at VGPR=56 is the sweet spot); per-wave
// scattered 16B stores doubled WRITE_SIZE (no coalescing + RMW fetches).
// So: keep r7's proven layout (48 gate-rows x 16 lanes, 32 f32 whh/lane,
// single-wave coalesced stores, dedicated poller waves tid>=768, fresh
// 4-deep ring per step), and change ONLY:
//  1) igates precomputed by GEMM (bias folded in); gate threads carry
//     ig_r/z/n in regs, prefetched for t+1 AFTER the comm store (consumed a
//     full step later -> store-ack + loads never on the critical path).
//     Deletes wih/xstage/stagers/isum + per-WG input re-stream (~1 GB).
//  2) raw lgkmcnt-only barriers (no __syncthreads vmcnt(0) drain): store-acks
//     and ring leftovers persist across steps; h_lds/gsum are LDS -> lgkmcnt
//     suffices for correctness; FIFO vmcnt keeps the counted ring exact.
// Comm protocol unchanged (r1-proven): tagged 8B words {val|step}, 2 per 16B
// line, parity double-buffered, sc0+sc1. Poll guard -> fast-fail, no hangs.

#define T_STEPS    32768
#define INSZ       256
#define HSZ        512
#define NWG        32
#define TPB        1024
#define POLL_GUARD 16384

typedef unsigned long long u64;
typedef unsigned int u32;
typedef u32 u32x4 __attribute__((ext_vector_type(4)));
typedef float f32x4 __attribute__((ext_vector_type(4)));
typedef float f32x2 __attribute__((ext_vector_type(2)));

__device__ __forceinline__ float grp_reduce16(float v) {
  v += __shfl_xor(v, 1);
  v += __shfl_xor(v, 2);
  v += __shfl_xor(v, 4);
  v += __shfl_xor(v, 8);
  return v;
}

// h_lds pad: +4 floats per 32 (16B-aligned, rotates bank groups) -- r7-proven
__device__ __forceinline__ int hpad(int k) { return k + 4 * (k >> 5); }

__device__ __forceinline__ void st16_sys(u64* p, u32x4 v) {
  asm volatile("global_store_dwordx4 %0, %1, off sc0 sc1" :: "v"(p), "v"(v) : "memory");
}

// raw workgroup barrier: flush LDS ops (lgkm) but do NOT drain vmcnt.
__device__ __forceinline__ void barrier_lds_only() {
  asm volatile("s_waitcnt lgkmcnt(0)\n\ts_barrier" ::: "memory");
}

// Re-init every call (harness does not re-poison d_ws between graph replays).
__global__ void init_comm(u64* __restrict__ comm, const float* __restrict__ h0) {
  int jj = threadIdx.x;                      // 0..511
  u32 bits = __float_as_uint(h0[jj]);
  comm[jj]       = (u64)bits;                // buf0: tag 0 | h0 value
  comm[HSZ + jj] = 0xFFFFFFFF00000000ull;    // buf1: invalid tag
}

// ---------------- Phase 1: igates GEMM (64x64 tiles, K=256; r8-proven) -----
__launch_bounds__(256)
__global__ void igates_gemm(const float* __restrict__ input,
                            const float* __restrict__ w_ih,
                            const float* __restrict__ bias,
                            float* __restrict__ ig)
{
  const int t0 = blockIdx.x * 64;
  const int r0 = blockIdx.y * 64;
  const int tid = threadIdx.x;
  const int tx = tid & 15, ty = tid >> 4;
  __shared__ float As[64][68];
  __shared__ float Bs[64][68];
  float acc[4][4] = {};
  for (int kc = 0; kc < INSZ; kc += 64) {
    #pragma unroll
    for (int i = 0; i < 4; ++i) {
      const int rr = (tid >> 4) + 16 * i;
      f32x4 av = *(const f32x4*)&input[(size_t)(t0 + rr) * INSZ + kc + tx * 4];
      *(f32x4*)&As[rr][tx * 4] = av;
      f32x4 bv = *(const f32x4*)&w_ih[(size_t)(r0 + rr) * INSZ + kc + tx * 4];
      #pragma unroll
      for (int ci = 0; ci < 4; ++ci) Bs[tx * 4 + ci][rr] = bv[ci];
    }
    __syncthreads();
    #pragma unroll 16
    for (int kk = 0; kk < 64; ++kk) {
      float av[4], bv[4];
      #pragma unroll
      for (int a = 0; a < 4; ++a) av[a] = As[ty * 4 + a][kk];
      #pragma unroll
      for (int b = 0; b < 4; ++b) bv[b] = Bs[kk][tx * 4 + b];
      #pragma unroll
      for (int a = 0; a < 4; ++a)
        #pragma unroll
        for (int b = 0; b < 4; ++b) acc[a][b] += av[a] * bv[b];
    }
    __syncthreads();
  }
  #pragma unroll
  for (int a = 0; a < 4; ++a)
    #pragma unroll
    for (int b = 0; b < 4; ++b) {
      const int r = r0 + tx * 4 + b;
      ig[(size_t)(t0 + ty * 4 + a) * 1536 + r] = acc[a][b] + bias[r];
    }
}

// ---------------- Phase 2: persistent recurrence (r7 layout) ----------------
__launch_bounds__(TPB, 1)
__global__ void gru_fast(const float* __restrict__ IG,     // [T][1536], bias folded
                         const float* __restrict__ init_hidden,
                         const float* __restrict__ w_hh,
                         const float* __restrict__ bias_n,
                         u64* __restrict__ comm,
                         float* __restrict__ out)
{
  const int tid = threadIdx.x;
  const int wg  = blockIdx.x;
  const int g   = tid >> 4;                             // 0..63
  const int l   = tid & 15;
  const bool mv = (g < 48);                             // matvec threads
  const int R   = wg * 16 + (g & 15) + 512 * (g >> 4);  // valid iff mv

  // ---- whh: 32 f32/lane (8 quads) -- the proven residency sweet spot ----
  f32x4 whh[8];
  if (mv) {
    const float* rp = w_hh + (size_t)R * HSZ + l * 32;
    #pragma unroll
    for (int c = 0; c < 8; ++c) whh[c] = *(const f32x4*)(rp + c * 4);
  }

  // ---- gate-thread state (tid<16): h_prev, bias_n, igates regs ----
  float hold = 0.f, bn = 0.f, ig_r = 0.f, ig_z = 0.f, ig_n = 0.f;
  if (tid < 16) {
    const int j = wg * 16 + tid;
    hold = init_hidden[j];
    bn   = bias_n[j];
    ig_r = IG[j];                 // step 0 igates (bias folded)
    ig_z = IG[512 + j];
    ig_n = IG[1024 + j];
  }

  __shared__ float h_lds[2][HSZ + 4 * (HSZ >> 5)];
  __shared__ float gsum[48];

  const bool poller = (tid >= 768);
  const int  pt     = tid - 768;          // 0..255
  u32x4 pa, pb, pc, pd, win;

#define ISSUE(Rr) \
  asm volatile("global_load_dwordx4 %0, %1, off sc0 sc1" : "=&v"(Rr) : "v"(lp) : "memory")
#define CHECK(Rr) \
  asm volatile("s_waitcnt vmcnt(3)" : "+v"(Rr)); \
  __builtin_amdgcn_sched_barrier(0); \
  if ((Rr[1] == tt && Rr[3] == tt) || --guard == 0) { win = Rr; break; } \
  ISSUE(Rr)

  for (int t = 0; t < T_STEPS; ++t) {
    const int p  = t & 1;
    const u32 tt = (u32)t;

    // ---- poll h_t (dedicated poller waves; fresh 4-deep ring, r7-proven) ----
    if (poller) {
      const u64* lp = comm + (size_t)p * HSZ + 2 * pt;
      ISSUE(pa); ISSUE(pb); ISSUE(pc); ISSUE(pd);
      int guard = POLL_GUARD;
      win = pa;
      for (;;) {
        CHECK(pa);
        CHECK(pb);
        CHECK(pc);
        CHECK(pd);
      }
      f32x2 hv;
      hv[0] = __uint_as_float(win[0]);
      hv[1] = __uint_as_float(win[2]);
      *(f32x2*)&h_lds[p][hpad(2 * pt)] = hv;
    }
    barrier_lds_only();   // sync1: h_lds[p] ready (no vmcnt drain)

    // ---- hh matvec: 32 MAC per mv thread (whh register-resident) ----
    if (mv) {
      float a = 0.f;
      const float* hp = &h_lds[p][l * 36];   // hpad(32l)
      #pragma unroll
      for (int c = 0; c < 8; ++c) {
        f32x4 hv4 = *(const f32x4*)(hp + c * 4);
        #pragma unroll
        for (int u = 0; u < 4; ++u) a += whh[c][u] * hv4[u];
      }
      a = grp_reduce16(a);
      if (l == 0) gsum[g] = a;
    }
    barrier_lds_only();   // sync2: gsum ready (no vmcnt drain)

    // ---- gates + coalesced broadcast + IG prefetch (tid<16 only) ----
    if (tid < 16) {
      const int j = tid;
      const float hr = gsum[j], hz = gsum[16 + j], hn = gsum[32 + j];
      const float reset = __builtin_amdgcn_rcpf(1.0f + __expf(-(ig_r + hr)));
      const float upd   = __builtin_amdgcn_rcpf(1.0f + __expf(-(ig_z + hz)));
      const float e2    = __expf(2.0f * (ig_n + reset * (hn + bn)));
      const float newv  = 1.0f - 2.0f * __builtin_amdgcn_rcpf(1.0f + e2);
      const float hnew  = newv + upd * (hold - newv);
      hold = hnew;
      const float hpair = __shfl(hnew, tid + 1);
      if ((j & 1) == 0) {
        // store FIRST (global critical path), one wave -> coalesced 16B x8
        u64* nbuf = comm + (size_t)((t + 1) & 1) * HSZ;
        u32x4 pk;
        pk[0] = __float_as_uint(hnew);  pk[1] = (u32)(t + 1);
        pk[2] = __float_as_uint(hpair); pk[3] = (u32)(t + 1);
        st16_sys(&nbuf[wg * 16 + j], pk);
        if (wg == 0 && j == 0) out[t] = hnew;
      }
      // IG prefetch for t+1: consumed a full step from now -> acks/loads
      // retire long before their wait; never on the critical path.
      const size_t bse = (size_t)((t + 1 < T_STEPS) ? (t + 1) : t) * 1536;
      const int jj = wg * 16 + tid;
      ig_r = IG[bse + jj];
      ig_z = IG[bse + 512 + jj];
      ig_n = IG[bse + 1024 + jj];
    }
  }
#undef ISSUE
#undef CHECK
  asm volatile("s_waitcnt vmcnt(0)" ::: "memory");   // drain ring before endpgm
}

// ---------------- Fallback: proven round-7 kernel (ws too small) ------------
#define TPB_FB 1024
__device__ __forceinline__ int xpad(int k) { return k + ((k >> 4) << 2); }

__launch_bounds__(TPB_FB, 1)
__global__ void gru_persistent_fb(const float* __restrict__ input,
                                  const float* __restrict__ init_hidden,
                                  const float* __restrict__ w_ih,
                                  const float* __restrict__ w_hh,
                                  const float* __restrict__ bias,
                                  const float* __restrict__ bias_n,
                                  u64* __restrict__ comm,
                                  float* __restrict__ out)
{
  const int tid = threadIdx.x;
  const int wg  = blockIdx.x;
  const int g   = tid >> 4;
  const int l   = tid & 15;
  const bool mv = (g < 48);
  const int R   = wg * 16 + (g & 15) + 512 * (g >> 4);

  f32x4 whh[8];
  f32x4 wih[4];
  if (mv) {
    const float* rp = w_hh + (size_t)R * HSZ + l * 32;
    #pragma unroll
    for (int c = 0; c < 8; ++c) whh[c] = *(const f32x4*)(rp + c * 4);
    const float* rp2 = w_ih + (size_t)R * INSZ + l * 16;
    #pragma unroll
    for (int c = 0; c < 4; ++c) wih[c] = *(const f32x4*)(rp2 + c * 4);
  }
  float hold = 0.f, b_r = 0.f, b_z = 0.f, b_n = 0.f, bn = 0.f;
  if (tid < 16) {
    const int j = wg * 16 + tid;
    hold = init_hidden[j];
    b_r  = bias[j]; b_z = bias[j + 512]; b_n = bias[j + 1024];
    bn   = bias_n[j];
  }
  __shared__ float h_lds[2][HSZ + 4 * (HSZ >> 5)];
  __shared__ float gsum[48];
  __shared__ float isum[2][48];
  __shared__ float xstage[INSZ + (INSZ >> 4) * 4];

  if (tid >= 64 && tid < 128) {
    const int s = tid - 64;
    f32x4 v = *(const f32x4*)(input + s * 4);
    *(f32x4*)&xstage[xpad(s * 4)] = v;
  }
  __syncthreads();
  if (mv) {
    float a = 0.f;
    #pragma unroll
    for (int c = 0; c < 4; ++c) {
      f32x4 xv = *(const f32x4*)&xstage[20 * l + 4 * c];
      #pragma unroll
      for (int u = 0; u < 4; ++u) a += wih[c][u] * xv[u];
    }
    a = grp_reduce16(a);
    if (l == 0) isum[0][g] = a;
  }
  const bool poller = (tid >= 768);
  const int  pt     = tid - 768;
  u32x4 pa, pb, pc, pd, win;

#define ISSUE(Rr) \
  asm volatile("global_load_dwordx4 %0, %1, off sc0 sc1" : "=&v"(Rr) : "v"(lp) : "memory")
#define CHECK(Rr) \
  asm volatile("s_waitcnt vmcnt(3)" : "+v"(Rr)); \
  __builtin_amdgcn_sched_barrier(0); \
  if ((Rr[1] == tt && Rr[3] == tt) || --guard == 0) { win = Rr; break; } \
  ISSUE(Rr)

  for (int t = 0; t < T_STEPS; ++t) {
    const int p  = t & 1;
    const u32 tt = (u32)t;
    f32x4 xnew = {0.f, 0.f, 0.f, 0.f};
    if (tid >= 64 && tid < 128) {
      const int tn = (t + 1 < T_STEPS) ? (t + 1) : (T_STEPS - 1);
      xnew = *(const f32x4*)(input + (size_t)tn * INSZ + (tid - 64) * 4);
    }
    if (poller) {
      const u64* lp = comm + (size_t)p * HSZ + 2 * pt;
      ISSUE(pa); ISSUE(pb); ISSUE(pc); ISSUE(pd);
      int guard = POLL_GUARD;
      win = pa;
      for (;;) {
        CHECK(pa);
        CHECK(pb);
        CHECK(pc);
        CHECK(pd);
      }
      f32x2 hv;
      hv[0] = __uint_as_float(win[0]);
      hv[1] = __uint_as_float(win[2]);
      *(f32x2*)&h_lds[p][hpad(2 * pt)] = hv;
    }
    __syncthreads();
    if (mv) {
      float a = 0.f;
      const float* hp = &h_lds[p][l * 36];
      #pragma unroll
      for (int c = 0; c < 8; ++c) {
        f32x4 hv4 = *(const f32x4*)(hp + c * 4);
        #pragma unroll
        for (int u = 0; u < 4; ++u) a += whh[c][u] * hv4[u];
      }
      a = grp_reduce16(a);
      if (l == 0) gsum[g] = a;
    }
    if (tid >= 64 && tid < 128) *(f32x4*)&xstage[xpad((tid - 64) * 4)] = xnew;
    __syncthreads();
    if (tid < 16) {
      const int j = tid;
      const float hr = gsum[j], hz = gsum[16 + j], hn = gsum[32 + j];
      const float i_r = isum[p][j], i_z = isum[p][16 + j], i_n = isum[p][32 + j];
      const float reset = __builtin_amdgcn_rcpf(1.0f + __expf(-(i_r + b_r + hr)));
      const float upd   = __builtin_amdgcn_rcpf(1.0f + __expf(-(i_z + b_z + hz)));
      const float e2    = __expf(2.0f * (i_n + b_n + reset * (hn + bn)));
      const float newv  = 1.0f - 2.0f * __builtin_amdgcn_rcpf(1.0f + e2);
      const float hnew  = newv + upd * (hold - newv);
      hold = hnew;
      const float hpair = __shfl(hnew, tid + 1);
      if ((j & 1) == 0) {
        u64* nbuf = comm + (size_t)((t + 1) & 1) * HSZ;
        u32x4 pk;
        pk[0] = __float_as_uint(hnew);  pk[1] = (u32)(t + 1);
        pk[2] = __float_as_uint(hpair); pk[3] = (u32)(t + 1);
        st16_sys(&nbuf[wg * 16 + j], pk);
        if (wg == 0 && j == 0) out[t] = hnew;
      }
    }
    if (mv) {
      float a2 = 0.f;
      #pragma unroll
      for (int c = 0; c < 4; ++c) {
        f32x4 xv = *(const f32x4*)&xstage[20 * l + 4 * c];
        #pragma unroll
        for (int u = 0; u < 4; ++u) a2 += wih[c][u] * xv[u];
      }
      a2 = grp_reduce16(a2);
      if (l == 0) isum[(t + 1) & 1][g] = a2;
    }
  }
#undef ISSUE
#undef CHECK
}

extern "C" void kernel_launch(void* const* d_in, const int* in_sizes, int n_in,
                              void* d_out, int out_size, void* d_ws, size_t ws_size,
                              hipStream_t stream) {
  const float* input  = (const float*)d_in[0];
  const float* h0     = (const float*)d_in[1];
  const float* w_ih   = (const float*)d_in[2];
  const float* w_hh   = (const float*)d_in[3];
  const float* bias   = (const float*)d_in[4];
  const float* bias_n = (const float*)d_in[5];
  float* out = (float*)d_out;

  const size_t IG_BYTES = (size_t)T_STEPS * 1536 * sizeof(float);  // 201.3 MB

  if (ws_size >= IG_BYTES + 16384) {
    float* ig  = (float*)d_ws;
    u64*  comm = (u64*)((char*)d_ws + IG_BYTES);
    hipLaunchKernelGGL(init_comm, dim3(1), dim3(HSZ), 0, stream, comm, h0);
    hipLaunchKernelGGL(igates_gemm, dim3(T_STEPS / 64, 1536 / 64), dim3(256),
                       0, stream, input, w_ih, bias, ig);
    hipLaunchKernelGGL(gru_fast, dim3(NWG), dim3(TPB), 0, stream,
                       ig, h0, w_hh, bias_n, comm, out);
  } else {
    u64* comm = (u64*)d_ws;
    hipLaunchKernelGGL(init_comm, dim3(1), dim3(HSZ), 0, stream, comm, h0);
    hipLaunchKernelGGL(gru_persistent_fb, dim3(NWG), dim3(TPB_FB), 0, stream,
                       input, h0, w_ih, w_hh, bias, bias_n, comm, out);
  }
}